// Round 2
// baseline (457.831 us; speedup 1.0000x reference)
//
#include <hip/hip_runtime.h>

#define THICKNESS 0.00047f

typedef float f4 __attribute__((ext_vector_type(4)));

// Pass 1 — one thread per face:
//  - gather 3 vertices (non-temporal: keep L2 free for partial buffers)
//  - compute StVK energy
//  - scatter energy/3 with WORKGROUP-scope atomics into the per-XCD partial
//    buffer (ws[xcd][v]); workgroup scope avoids the sc1 L2-bypass that
//    device-scope atomics need for cross-XCD coherence, so the RMW executes
//    in the local XCD's L2 (4 MB buffer == L2 size, stays resident since all
//    other traffic is marked non-temporal). Safe because each buffer is only
//    ever touched by blocks on its own XCD.
//  - block-reduce energy -> 1 device-scope atomicAdd into loss
__global__ __launch_bounds__(256) void face_energy_k1(
    const float* __restrict__ pred_pos,    // [V,3]
    const int*   __restrict__ faces,       // [F,3]
    const float* __restrict__ Dm_inv,      // [F,2,2]
    const float* __restrict__ f_area,      // [F,1]
    const float* __restrict__ lame_mu,     // [1]
    const float* __restrict__ lame_lambda, // [1]
    float* __restrict__ out,               // [0]=loss, [1..V]=per_vert (fallback path)
    float* __restrict__ partial,           // [8][V] per-XCD accumulators (or unused)
    int F, int V, int use_partial)
{
    const int f = blockIdx.x * blockDim.x + threadIdx.x;

    float energy = 0.0f;
    int i0 = 0, i1 = 0, i2 = 0;

    if (f < F) {
        i0 = __builtin_nontemporal_load(faces + 3 * f + 0);
        i1 = __builtin_nontemporal_load(faces + 3 * f + 1);
        i2 = __builtin_nontemporal_load(faces + 3 * f + 2);

        // gather vertices (non-temporal: random, ~0 reuse inside one L2)
        const float v0x = __builtin_nontemporal_load(pred_pos + 3 * i0 + 0);
        const float v0y = __builtin_nontemporal_load(pred_pos + 3 * i0 + 1);
        const float v0z = __builtin_nontemporal_load(pred_pos + 3 * i0 + 2);
        const float v1x = __builtin_nontemporal_load(pred_pos + 3 * i1 + 0);
        const float v1y = __builtin_nontemporal_load(pred_pos + 3 * i1 + 1);
        const float v1z = __builtin_nontemporal_load(pred_pos + 3 * i1 + 2);
        const float v2x = __builtin_nontemporal_load(pred_pos + 3 * i2 + 0);
        const float v2y = __builtin_nontemporal_load(pred_pos + 3 * i2 + 1);
        const float v2z = __builtin_nontemporal_load(pred_pos + 3 * i2 + 2);

        const float d0x = v0x - v2x, d0y = v0y - v2y, d0z = v0z - v2z;
        const float d1x = v1x - v2x, d1y = v1y - v2y, d1z = v1z - v2z;

        const f4 m = __builtin_nontemporal_load(
            reinterpret_cast<const f4*>(Dm_inv + 4 * f));
        const float m00 = m.x, m01 = m.y, m10 = m.z, m11 = m.w;

        const float F0x = d0x * m00 + d1x * m10;
        const float F0y = d0y * m00 + d1y * m10;
        const float F0z = d0z * m00 + d1z * m10;
        const float F1x = d0x * m01 + d1x * m11;
        const float F1y = d0y * m01 + d1y * m11;
        const float F1z = d0z * m01 + d1z * m11;

        const float a = F0x * F0x + F0y * F0y + F0z * F0z;
        const float b = F0x * F1x + F0y * F1y + F0z * F1z;
        const float c = F1x * F1x + F1y * F1y + F1z * F1z;
        const float G00 = 0.5f * (a - 1.0f);
        const float G01 = 0.5f * b;
        const float G11 = 0.5f * (c - 1.0f);
        const float tr  = G00 + G11;

        const float mu  = lame_mu[0];
        const float lam = lame_lambda[0];

        const float density = mu * (G00 * G00 + 2.0f * G01 * G01 + G11 * G11)
                            + 0.5f * lam * tr * tr;

        energy = __builtin_nontemporal_load(f_area + f) * THICKNESS * density;
    }

    if (f < F) {
        const float e3 = energy * (1.0f / 3.0f);
        if (use_partial) {
            unsigned xcd;
            asm volatile("s_getreg_b32 %0, hwreg(HW_REG_XCC_ID)" : "=s"(xcd));
            float* my = partial + (size_t)(xcd & 7u) * (size_t)V;
            __hip_atomic_fetch_add(my + i0, e3, __ATOMIC_RELAXED, __HIP_MEMORY_SCOPE_WORKGROUP);
            __hip_atomic_fetch_add(my + i1, e3, __ATOMIC_RELAXED, __HIP_MEMORY_SCOPE_WORKGROUP);
            __hip_atomic_fetch_add(my + i2, e3, __ATOMIC_RELAXED, __HIP_MEMORY_SCOPE_WORKGROUP);
        } else {
            atomicAdd(&out[1 + i0], e3);
            atomicAdd(&out[1 + i1], e3);
            atomicAdd(&out[1 + i2], e3);
        }
    }

    // ---- block reduction of energy for the loss ----
    float v = energy;
    #pragma unroll
    for (int off = 32; off > 0; off >>= 1)
        v += __shfl_down(v, off, 64);

    __shared__ float wsum[4];
    const int lane = threadIdx.x & 63;
    const int wave = threadIdx.x >> 6;
    if (lane == 0) wsum[wave] = v;
    __syncthreads();
    if (threadIdx.x == 0) {
        atomicAdd(&out[0], wsum[0] + wsum[1] + wsum[2] + wsum[3]);
    }
}

// Pass 2 — sum the 8 per-XCD partials into out[1..V]. 32 MB read, 4 MB write.
__global__ __launch_bounds__(256) void reduce_k2(
    const float* __restrict__ partial, float* __restrict__ out, int V)
{
    const int t  = blockIdx.x * blockDim.x + threadIdx.x;
    const int v4 = t * 4;
    if (v4 + 3 < V) {
        f4 s = {0.f, 0.f, 0.f, 0.f};
        #pragma unroll
        for (int k = 0; k < 8; ++k)
            s += *reinterpret_cast<const f4*>(partial + (size_t)k * V + v4);
        out[1 + v4 + 0] = s.x;
        out[1 + v4 + 1] = s.y;
        out[1 + v4 + 2] = s.z;
        out[1 + v4 + 3] = s.w;
    } else {
        for (int v = v4; v < V; ++v) {
            float s = 0.f;
            #pragma unroll
            for (int k = 0; k < 8; ++k) s += partial[(size_t)k * V + v];
            out[1 + v] = s;
        }
    }
}

extern "C" void kernel_launch(void* const* d_in, const int* in_sizes, int n_in,
                              void* d_out, int out_size, void* d_ws, size_t ws_size,
                              hipStream_t stream) {
    const float* pred_pos    = (const float*)d_in[0];
    const int*   faces       = (const int*)  d_in[1];
    const float* Dm_inv      = (const float*)d_in[2];
    const float* f_area      = (const float*)d_in[3];
    const float* lame_mu     = (const float*)d_in[4];
    const float* lame_lambda = (const float*)d_in[5];
    float* out = (float*)d_out;

    const int V = in_sizes[0] / 3;
    const int F = in_sizes[1] / 3;

    const size_t need = (size_t)8 * (size_t)V * sizeof(float);
    const int use_partial = (ws_size >= need) ? 1 : 0;

    if (use_partial) {
        hipMemsetAsync(d_ws, 0, need, stream);
        hipMemsetAsync(d_out, 0, sizeof(float), stream);  // loss; k2 overwrites per_vert
    } else {
        hipMemsetAsync(d_out, 0, (size_t)out_size * sizeof(float), stream);
    }

    const int block = 256;
    const int grid1 = (F + block - 1) / block;
    face_energy_k1<<<grid1, block, 0, stream>>>(
        pred_pos, faces, Dm_inv, f_area, lame_mu, lame_lambda,
        out, (float*)d_ws, F, V, use_partial);

    if (use_partial) {
        const int nt    = (V + 3) / 4;
        const int grid2 = (nt + block - 1) / block;
        reduce_k2<<<grid2, block, 0, stream>>>((const float*)d_ws, out, V);
    }
}

// Round 4
// 413.225 us; speedup vs baseline: 1.1079x; 1.1079x over previous
//
#include <hip/hip_runtime.h>

#define THICKNESS 0.00047f

typedef float f4 __attribute__((ext_vector_type(4)));
typedef int   i4 __attribute__((ext_vector_type(4)));

#define NT_LOAD(p) __builtin_nontemporal_load(p)

// 4 faces per thread:
//  - streaming inputs loaded as wide non-temporal vectors (read-once; keep L2
//    free for the pred_pos gather working set, which has ~6x reuse/vertex)
//  - 12 vertex gathers issued before any consumption -> 4x MLP per wave
//  - 12 device-scope atomicAdds into per_vert (fixed fabric cost, see R2)
//  - block-reduced loss -> 1 atomicAdd
__global__ __launch_bounds__(256) void face_energy_k(
    const float* __restrict__ pred_pos,    // [V,3]
    const int*   __restrict__ faces,       // [F,3]
    const float* __restrict__ Dm_inv,      // [F,2,2]
    const float* __restrict__ f_area,      // [F,1]
    const float* __restrict__ lame_mu,     // [1]
    const float* __restrict__ lame_lambda, // [1]
    float* __restrict__ out,               // [0]=loss, [1..V]=per_vert
    int F)
{
    const int t    = blockIdx.x * blockDim.x + threadIdx.x;
    const int base = t * 4;

    const float mu  = lame_mu[0];
    const float lam = lame_lambda[0];

    float esum = 0.0f;

    if (base + 3 < F) {
        // ---- streaming loads, fully vectorized ----
        const i4* fptr = reinterpret_cast<const i4*>(faces + 3 * base); // 48B, 16B-aligned
        const i4 fa = NT_LOAD(fptr + 0);
        const i4 fb = NT_LOAD(fptr + 1);
        const i4 fc = NT_LOAD(fptr + 2);
        const int idx[4][3] = {
            { fa.x, fa.y, fa.z },
            { fa.w, fb.x, fb.y },
            { fb.z, fb.w, fc.x },
            { fc.y, fc.z, fc.w },
        };

        const f4* mptr = reinterpret_cast<const f4*>(Dm_inv + 4 * base);
        f4 m[4];
        #pragma unroll
        for (int k = 0; k < 4; ++k) m[k] = NT_LOAD(mptr + k);

        const f4 area = NT_LOAD(reinterpret_cast<const f4*>(f_area + base));
        const float ar[4] = { area.x, area.y, area.z, area.w };

        // ---- issue all 12 vertex gathers (cached: pred_pos has reuse) ----
        float px[4][3], py[4][3], pz[4][3];
        #pragma unroll
        for (int k = 0; k < 4; ++k) {
            #pragma unroll
            for (int j = 0; j < 3; ++j) {
                const int vi = idx[k][j];
                px[k][j] = pred_pos[3 * vi + 0];
                py[k][j] = pred_pos[3 * vi + 1];
                pz[k][j] = pred_pos[3 * vi + 2];
            }
        }

        // ---- compute + scatter ----
        #pragma unroll
        for (int k = 0; k < 4; ++k) {
            const float d0x = px[k][0] - px[k][2], d0y = py[k][0] - py[k][2], d0z = pz[k][0] - pz[k][2];
            const float d1x = px[k][1] - px[k][2], d1y = py[k][1] - py[k][2], d1z = pz[k][1] - pz[k][2];

            const float m00 = m[k].x, m01 = m[k].y, m10 = m[k].z, m11 = m[k].w;

            const float F0x = d0x * m00 + d1x * m10;
            const float F0y = d0y * m00 + d1y * m10;
            const float F0z = d0z * m00 + d1z * m10;
            const float F1x = d0x * m01 + d1x * m11;
            const float F1y = d0y * m01 + d1y * m11;
            const float F1z = d0z * m01 + d1z * m11;

            const float a = F0x * F0x + F0y * F0y + F0z * F0z;
            const float b = F0x * F1x + F0y * F1y + F0z * F1z;
            const float c = F1x * F1x + F1y * F1y + F1z * F1z;
            const float G00 = 0.5f * (a - 1.0f);
            const float G01 = 0.5f * b;
            const float G11 = 0.5f * (c - 1.0f);
            const float tr  = G00 + G11;

            const float density = mu * (G00 * G00 + 2.0f * G01 * G01 + G11 * G11)
                                + 0.5f * lam * tr * tr;

            const float e  = ar[k] * THICKNESS * density;
            const float e3 = e * (1.0f / 3.0f);
            esum += e;

            atomicAdd(&out[1 + idx[k][0]], e3);
            atomicAdd(&out[1 + idx[k][1]], e3);
            atomicAdd(&out[1 + idx[k][2]], e3);
        }
    } else if (base < F) {
        // ---- scalar tail ----
        for (int f = base; f < F; ++f) {
            const int i0 = faces[3 * f + 0];
            const int i1 = faces[3 * f + 1];
            const int i2 = faces[3 * f + 2];

            const float v0x = pred_pos[3 * i0 + 0], v0y = pred_pos[3 * i0 + 1], v0z = pred_pos[3 * i0 + 2];
            const float v1x = pred_pos[3 * i1 + 0], v1y = pred_pos[3 * i1 + 1], v1z = pred_pos[3 * i1 + 2];
            const float v2x = pred_pos[3 * i2 + 0], v2y = pred_pos[3 * i2 + 1], v2z = pred_pos[3 * i2 + 2];

            const float d0x = v0x - v2x, d0y = v0y - v2y, d0z = v0z - v2z;
            const float d1x = v1x - v2x, d1y = v1y - v2y, d1z = v1z - v2z;

            const float m00 = Dm_inv[4 * f + 0], m01 = Dm_inv[4 * f + 1];
            const float m10 = Dm_inv[4 * f + 2], m11 = Dm_inv[4 * f + 3];

            const float F0x = d0x * m00 + d1x * m10;
            const float F0y = d0y * m00 + d1y * m10;
            const float F0z = d0z * m00 + d1z * m10;
            const float F1x = d0x * m01 + d1x * m11;
            const float F1y = d0y * m01 + d1y * m11;
            const float F1z = d0z * m01 + d1z * m11;

            const float a = F0x * F0x + F0y * F0y + F0z * F0z;
            const float b = F0x * F1x + F0y * F1y + F0z * F1z;
            const float c = F1x * F1x + F1y * F1y + F1z * F1z;
            const float G00 = 0.5f * (a - 1.0f);
            const float G01 = 0.5f * b;
            const float G11 = 0.5f * (c - 1.0f);
            const float tr  = G00 + G11;

            const float density = mu * (G00 * G00 + 2.0f * G01 * G01 + G11 * G11)
                                + 0.5f * lam * tr * tr;

            const float e  = f_area[f] * THICKNESS * density;
            const float e3 = e * (1.0f / 3.0f);
            esum += e;

            atomicAdd(&out[1 + i0], e3);
            atomicAdd(&out[1 + i1], e3);
            atomicAdd(&out[1 + i2], e3);
        }
    }

    // ---- block reduction of esum for the loss ----
    float v = esum;
    #pragma unroll
    for (int off = 32; off > 0; off >>= 1)
        v += __shfl_down(v, off, 64);

    __shared__ float wsum[4];
    const int lane = threadIdx.x & 63;
    const int wave = threadIdx.x >> 6;
    if (lane == 0) wsum[wave] = v;
    __syncthreads();
    if (threadIdx.x == 0) {
        atomicAdd(&out[0], wsum[0] + wsum[1] + wsum[2] + wsum[3]);
    }
}

extern "C" void kernel_launch(void* const* d_in, const int* in_sizes, int n_in,
                              void* d_out, int out_size, void* d_ws, size_t ws_size,
                              hipStream_t stream) {
    const float* pred_pos    = (const float*)d_in[0];
    const int*   faces       = (const int*)  d_in[1];
    const float* Dm_inv      = (const float*)d_in[2];
    const float* f_area      = (const float*)d_in[3];
    const float* lame_mu     = (const float*)d_in[4];
    const float* lame_lambda = (const float*)d_in[5];
    float* out = (float*)d_out;

    const int F = in_sizes[1] / 3;

    // atomics accumulate into d_out -> must start at zero (harness poisons 0xAA)
    (void)hipMemsetAsync(d_out, 0, (size_t)out_size * sizeof(float), stream);

    const int block   = 256;
    const int threads = (F + 3) / 4;
    const int grid    = (threads + block - 1) / block;
    face_energy_k<<<grid, block, 0, stream>>>(
        pred_pos, faces, Dm_inv, f_area, lame_mu, lame_lambda, out, F);
}